// Round 14
// baseline (332.663 us; speedup 1.0000x reference)
//
#include <hip/hip_runtime.h>
#include <hip/hip_bf16.h>
#include <stdint.h>

#define T_TOK 2048
#define HDIM  1024
#define IDIM  3584
#define NEXP  8
#define NROWS 4096      // T_TOK * TOP_K
#define WELEM 29360128  // elements per weight tensor (8*3584*1024)
#define NJOBS 40        // max (expert,rowtile) jobs: 32 + 7 rounding
#define CVTB  512       // cvt-w2 blocks appended to mlp_in grid

typedef __attribute__((ext_vector_type(8))) short bf16x8;
typedef __attribute__((ext_vector_type(4))) float f32x4;

typedef __attribute__((address_space(3))) unsigned lds_u32;
typedef const __attribute__((address_space(1))) unsigned glb_u32;

#define MFMA16 __builtin_amdgcn_mfma_f32_16x16x32_bf16

__device__ __forceinline__ unsigned short f2bf(float f){
  union { float f; unsigned u; } v; v.f = f;
  unsigned r = v.u + 0x7FFFu + ((v.u >> 16) & 1u);   // RNE
  return (unsigned short)(r >> 16);
}
__device__ __forceinline__ unsigned cvt2(float a, float b){
  __hip_bfloat162 h = __float22bfloat162_rn(float2{a, b});
  return *reinterpret_cast<unsigned*>(&h);
}

// ---------------- Kernel 1: RMSNorm + router ----------------
__global__ __launch_bounds__(256) void k_rms_router(
    const float* __restrict__ x, const float* __restrict__ rmsw,
    const float* __restrict__ gw, unsigned short* __restrict__ h_bf,
    int* __restrict__ topk_i, float* __restrict__ topk_w, int* __restrict__ count)
{
  const int t = blockIdx.x, tid = threadIdx.x;
  const int lane = tid & 63, wid = tid >> 6;
  float4 x4 = reinterpret_cast<const float4*>(x)[t*256 + tid];
  float ss = x4.x*x4.x + x4.y*x4.y + x4.z*x4.z + x4.w*x4.w;
  #pragma unroll
  for (int o = 32; o >= 1; o >>= 1) ss += __shfl_xor(ss, o);
  __shared__ float sred[4];
  __shared__ float slog[32];
  if (lane == 0) sred[wid] = ss;
  __syncthreads();
  float inv = rsqrtf((sred[0]+sred[1]+sred[2]+sred[3]) * (1.0f/HDIM) + 1e-6f);
  float4 w4 = reinterpret_cast<const float4*>(rmsw)[tid];
  float h0 = x4.x*inv*w4.x, h1 = x4.y*inv*w4.y, h2 = x4.z*inv*w4.z, h3 = x4.w*inv*w4.w;
  ushort4 hb; hb.x = f2bf(h0); hb.y = f2bf(h1); hb.z = f2bf(h2); hb.w = f2bf(h3);
  reinterpret_cast<ushort4*>(h_bf)[t*256 + tid] = hb;
  #pragma unroll
  for (int e = 0; e < NEXP; e++){
    float4 g4 = reinterpret_cast<const float4*>(gw)[e*256 + tid];
    float v = h0*g4.x + h1*g4.y + h2*g4.z + h3*g4.w;
    #pragma unroll
    for (int o = 32; o >= 1; o >>= 1) v += __shfl_xor(v, o);
    if (lane == 0) slog[e*4 + wid] = v;
  }
  __syncthreads();
  if (tid == 0){
    float lg[NEXP];
    #pragma unroll
    for (int e = 0; e < NEXP; e++) lg[e] = slog[e*4]+slog[e*4+1]+slog[e*4+2]+slog[e*4+3];
    int i0 = 0;
    for (int e = 1; e < NEXP; e++) if (lg[e] > lg[i0]) i0 = e;   // ties -> lowest index
    int i1 = -1;
    for (int e = 0; e < NEXP; e++){ if (e == i0) continue; if (i1 < 0 || lg[e] > lg[i1]) i1 = e; }
    float m  = fmaxf(lg[i0], lg[i1]);
    float e0 = expf(lg[i0]-m), e1 = expf(lg[i1]-m);
    float s  = e0 + e1;
    topk_i[t*2] = i0; topk_i[t*2+1] = i1;
    topk_w[t*2] = e0/s; topk_w[t*2+1] = e1/s;
    atomicAdd(&count[i0], 1); atomicAdd(&count[i1], 1);
  }
}

// ---------------- Kernel 1b: streaming cvt of w1+w3, x4 unrolled ----------------
// grid 1792 x 256: 1792*256*4*4 == WELEM/4 exactly (no bounds checks).
__global__ __launch_bounds__(256) void k_cvt13(
    const float4* __restrict__ a, const float4* __restrict__ b,
    uint2* __restrict__ da, uint2* __restrict__ db)
{
  size_t base = ((size_t)blockIdx.x*256 + threadIdx.x)*4;
  const size_t stride = (size_t)1792*256*4;
  #pragma unroll
  for (int it = 0; it < 4; it++){
    float4 va0 = a[base+0], va1 = a[base+1], va2 = a[base+2], va3 = a[base+3];
    float4 vb0 = b[base+0], vb1 = b[base+1], vb2 = b[base+2], vb3 = b[base+3];
    da[base+0] = make_uint2(cvt2(va0.x,va0.y), cvt2(va0.z,va0.w));
    da[base+1] = make_uint2(cvt2(va1.x,va1.y), cvt2(va1.z,va1.w));
    da[base+2] = make_uint2(cvt2(va2.x,va2.y), cvt2(va2.z,va2.w));
    da[base+3] = make_uint2(cvt2(va3.x,va3.y), cvt2(va3.z,va3.w));
    db[base+0] = make_uint2(cvt2(vb0.x,vb0.y), cvt2(vb0.z,vb0.w));
    db[base+1] = make_uint2(cvt2(vb1.x,vb1.y), cvt2(vb1.z,vb1.w));
    db[base+2] = make_uint2(cvt2(vb2.x,vb2.y), cvt2(vb2.z,vb2.w));
    db[base+3] = make_uint2(cvt2(vb3.x,vb3.y), cvt2(vb3.z,vb3.w));
    base += stride;
  }
}

// ---------------- Kernel 2: offsets + job list ----------------
__global__ void k_scan(const int* __restrict__ count, int* __restrict__ offset,
                       int* __restrict__ jobs){
  if (threadIdx.x == 0){
    int o = 0, L = 0;
    for (int e = 0; e < NEXP; e++){
      offset[e] = o;
      int nrt = (count[e] + 127) >> 7;
      for (int r = 0; r < nrt && L < NJOBS; r++) jobs[L++] = (e << 8) | r;
      o += count[e];
    }
    for (; L < NJOBS; L++) jobs[L] = -1;
  }
}

// ---------------- Kernel 3: scatter ----------------
__global__ __launch_bounds__(256) void k_scatter(
    const int* __restrict__ topk_i, const float* __restrict__ topk_w,
    const int* __restrict__ offset, int* __restrict__ cursor,
    int* __restrict__ token_of_row, float* __restrict__ wrow, int* __restrict__ slot_of)
{
  int t = blockIdx.x*256 + threadIdx.x;
  if (t >= T_TOK) return;
  #pragma unroll
  for (int k = 0; k < 2; k++){
    int e = topk_i[t*2+k];
    int pos = atomicAdd(&cursor[e], 1);
    int row = offset[e] + pos;
    token_of_row[row] = t;
    wrow[row] = topk_w[t*2+k];
    slot_of[t*2+k] = row;
  }
}

// ---------------- Kernel: fp32 -> bf16 (standalone, fallback path) ----------------
__global__ __launch_bounds__(256) void k_cvt(
    const float4* __restrict__ src, uint2* __restrict__ dst, int n4)
{
  int stride = gridDim.x * blockDim.x;
  for (int i = blockIdx.x*blockDim.x + threadIdx.x; i < n4; i += stride){
    float4 v = src[i];
    dst[i] = make_uint2(cvt2(v.x, v.y), cvt2(v.z, v.w));
  }
}

// =====================================================================
// Kernel 4: fused w1/w3 GEMM + SwiGLU  (R9-exact core, work-list grid)
// Tile 128 rows x 64 cols, BK=64, 256 thr / 4 waves (2x2), wave 64x32.
// d = t*56 + p  (p = panel 0..55, t = job 0..39); all consumers of panel p
// land on XCD p%8 (56 == 0 mod 8). Blocks d >= 2240 stream-convert w2.
// =====================================================================
__global__ __launch_bounds__(256, 3) void k_mlp_in(
    const unsigned short* __restrict__ h_bf, const unsigned short* __restrict__ w1bf,
    const unsigned short* __restrict__ w3bf, const int* __restrict__ token_of_row,
    const int* __restrict__ count, const int* __restrict__ offset,
    const int* __restrict__ jobs, unsigned short* __restrict__ act,
    const float4* __restrict__ w2s, uint2* __restrict__ w2d)
{
  const int d = blockIdx.x;
  const int tid = threadIdx.x;
  if (d >= NJOBS*56){
    // ---- cvt-w2 role (only present when 3 bf16 buffers fit in ws) ----
    if (w2d){
      int i0 = (d - NJOBS*56)*256 + tid;
      for (int i = i0; i < WELEM/4; i += CVTB*256){
        float4 v = w2s[i];
        w2d[i] = make_uint2(cvt2(v.x, v.y), cvt2(v.z, v.w));
      }
    }
    return;
  }
  const int p = d % 56;
  const int t = d / 56;
  const int job = jobs[t];
  if (job < 0) return;
  const int e = job >> 8, rt = job & 255;
  const int cnt = count[e];
  const int off = offset[e], row0 = off + rt*128, rend = off + cnt;
  const int col0 = p * 64;
  const int lane = tid & 63, wid = tid >> 6;
  const int wave_r = wid >> 1, wave_c = wid & 1;

  __shared__ __align__(16) char sA [16384];  // 128 rows x 64 k bf16 (swizzled)
  __shared__ __align__(16) char sB1[8192];   // 64 cols x 64 k bf16
  __shared__ __align__(16) char sB2[8192];

  const int srow = tid >> 3;                // 0..31
  const int sg   = (tid & 7) ^ (srow & 7);  // pre-swizzled logical k-chunk

  const unsigned short* aptr[4];
  #pragma unroll
  for (int j = 0; j < 4; j++){
    int tok = token_of_row[min(row0 + srow + 32*j, NROWS-1)];
    aptr[j] = h_bf + (size_t)tok*HDIM + sg*8;
  }
  const unsigned short* b1ptr[2];
  const unsigned short* b3ptr[2];
  #pragma unroll
  for (int j = 0; j < 2; j++){
    int col = col0 + srow + 32*j;
    b1ptr[j] = w1bf + (size_t)(e*IDIM + col)*HDIM + sg*8;
    b3ptr[j] = w3bf + (size_t)(e*IDIM + col)*HDIM + sg*8;
  }

  #define ISSUE(kk) {                                                                \
    _Pragma("unroll")                                                                \
    for (int j = 0; j < 4; j++)                                                      \
      __builtin_amdgcn_global_load_lds((glb_u32*)(const void*)(aptr[j] + (kk)*64),   \
          (lds_u32*)(void*)(sA + j*4096 + tid*16), 16, 0, 0);                        \
    _Pragma("unroll")                                                                \
    for (int j = 0; j < 2; j++){                                                     \
      __builtin_amdgcn_global_load_lds((glb_u32*)(const void*)(b1ptr[j] + (kk)*64),  \
          (lds_u32*)(void*)(sB1 + j*4096 + tid*16), 16, 0, 0);                       \
      __builtin_amdgcn_global_load_lds((glb_u32*)(const void*)(b3ptr[j] + (kk)*64),  \
          (lds_u32*)(void*)(sB2 + j*4096 + tid*16), 16, 0, 0);                       \
    } }

  f32x4 acc1[4][2], acc3[4][2];
  #pragma unroll
  for (int m = 0; m < 4; m++)
    #pragma unroll
    for (int n = 0; n < 2; n++){
      acc1[m][n] = (f32x4){0.f,0.f,0.f,0.f};
      acc3[m][n] = (f32x4){0.f,0.f,0.f,0.f};
    }

  for (int kk = 0; kk < HDIM/64; kk++){
    ISSUE(kk);
    __syncthreads();          // drains vmcnt: tile kk ready (m97 pattern)
    #pragma unroll
    for (int ki = 0; ki < 2; ki++){
      bf16x8 af[4];
      #pragma unroll
      for (int m = 0; m < 4; m++){
        int row = wave_r*64 + m*16 + (lane & 15);
        int slot = ki*4 + (lane >> 4);
        af[m] = *reinterpret_cast<const bf16x8*>(sA + row*128 + ((slot ^ (row&7))<<4));
      }
      #pragma unroll
      for (int n = 0; n < 2; n++){
        int col = wave_c*32 + n*16 + (lane & 15);
        int slot = ki*4 + (lane >> 4);
        bf16x8 b1 = *reinterpret_cast<const bf16x8*>(sB1 + col*128 + ((slot ^ (col&7))<<4));
        bf16x8 b2 = *reinterpret_cast<const bf16x8*>(sB2 + col*128 + ((slot ^ (col&7))<<4));
        #pragma unroll
        for (int m = 0; m < 4; m++){
          acc1[m][n] = MFMA16(af[m], b1, acc1[m][n], 0,0,0);
          acc3[m][n] = MFMA16(af[m], b2, acc3[m][n], 0,0,0);
        }
      }
    }
    __syncthreads();          // reads done before next overwrite
  }

  const int lcol = lane & 15, lrow4 = (lane >> 4) * 4;
  #pragma unroll
  for (int m = 0; m < 4; m++){
    #pragma unroll
    for (int n = 0; n < 2; n++){
      int gcol = col0 + wave_c*32 + n*16 + lcol;
      #pragma unroll
      for (int r = 0; r < 4; r++){
        int grow = row0 + wave_r*64 + m*16 + lrow4 + r;
        if (grow < rend){
          float a = acc1[m][n][r], g = acc3[m][n][r];
          float sig = 1.0f / (1.0f + __expf(-a));
          act[(size_t)grow*IDIM + gcol] = f2bf(a * sig * g);
        }
      }
    }
  }
  #undef ISSUE
}

// =====================================================================
// Kernel 5: w2 GEMM, BK=128 (28 K-steps), 16-slot XOR swizzle.
// Tile 128 rows x 64 cols, 256 thr / 4 waves (2x2), wave 64x32.
// LDS 48KB -> 3 blocks/CU. d = t*16 + p  (panel-XCD pin: 16 == 0 mod 8).
// =====================================================================
__global__ __launch_bounds__(256, 3) void k_mlp_out(
    const unsigned short* __restrict__ act, const unsigned short* __restrict__ w2bf,
    const float* __restrict__ wrow, const int* __restrict__ count,
    const int* __restrict__ offset, const int* __restrict__ jobs,
    float* __restrict__ eo)
{
  const int d = blockIdx.x;
  const int p = d & 15;
  const int t = d >> 4;
  const int job = jobs[t];
  if (job < 0) return;
  const int e = job >> 8, rt = job & 255;
  const int cnt = count[e];
  const int off = offset[e], row0 = off + rt*128, rend = off + cnt;
  const int col0 = p * 64;
  const int tid = threadIdx.x, lane = tid & 63, wid = tid >> 6;
  const int wave_r = wid >> 1, wave_c = wid & 1;

  __shared__ __align__(16) char sA[32768];   // 128 rows x 128 k bf16 (256B rows, swizzled)
  __shared__ __align__(16) char sB[16384];   // 64 cols x 128 k bf16

  const int sr16 = tid >> 4;            // 0..15
  const int sg   = (tid & 15) ^ sr16;   // pre-swizzled logical 16B slot

  const unsigned short* aptr[8];
  #pragma unroll
  for (int j = 0; j < 8; j++){
    int r = min(row0 + j*16 + sr16, NROWS-1);
    aptr[j] = act + (size_t)r*IDIM + sg*8;
  }
  const unsigned short* bptr[4];
  #pragma unroll
  for (int j = 0; j < 4; j++){
    int col = col0 + j*16 + sr16;
    bptr[j] = w2bf + (size_t)(e*HDIM + col)*IDIM + sg*8;
  }

  #define ISSUE(kk) {                                                                \
    _Pragma("unroll")                                                                \
    for (int j = 0; j < 8; j++)                                                      \
      __builtin_amdgcn_global_load_lds((glb_u32*)(const void*)(aptr[j] + (kk)*128),  \
          (lds_u32*)(void*)(sA + j*4096 + tid*16), 16, 0, 0);                        \
    _Pragma("unroll")                                                                \
    for (int j = 0; j < 4; j++)                                                      \
      __builtin_amdgcn_global_load_lds((glb_u32*)(const void*)(bptr[j] + (kk)*128),  \
          (lds_u32*)(void*)(sB + j*4096 + tid*16), 16, 0, 0); }

  f32x4 acc[4][2];
  #pragma unroll
  for (int m = 0; m < 4; m++)
    #pragma unroll
    for (int n = 0; n < 2; n++) acc[m][n] = (f32x4){0.f,0.f,0.f,0.f};

  for (int kk = 0; kk < IDIM/128; kk++){
    ISSUE(kk);
    __syncthreads();
    #pragma unroll
    for (int ki = 0; ki < 4; ki++){
      bf16x8 af[4];
      #pragma unroll
      for (int m = 0; m < 4; m++){
        int row = wave_r*64 + m*16 + (lane & 15);
        int slot = ki*4 + (lane >> 4);
        af[m] = *reinterpret_cast<const bf16x8*>(sA + row*256 + ((slot ^ (row&15))<<4));
      }
      #pragma unroll
      for (int n = 0; n < 2; n++){
        int col = wave_c*32 + n*16 + (lane & 15);
        int slot = ki*4 + (lane >> 4);
        bf16x8 fb = *reinterpret_cast<const bf16x8*>(sB + col*256 + ((slot ^ (col&15))<<4));
        #pragma unroll
        for (int m = 0; m < 4; m++)
          acc[m][n] = MFMA16(af[m], fb, acc[m][n], 0,0,0);
      }
    }
    __syncthreads();
  }

  const int lcol = lane & 15, lrow4 = (lane >> 4) * 4;
  #pragma unroll
  for (int m = 0; m < 4; m++){
    #pragma unroll
    for (int n = 0; n < 2; n++){
      int gcol = col0 + wave_c*32 + n*16 + lcol;
      #pragma unroll
      for (int r = 0; r < 4; r++){
        int grow = row0 + wave_r*64 + m*16 + lrow4 + r;
        if (grow < rend){
          eo[(size_t)grow*HDIM + gcol] = acc[m][n][r] * wrow[grow];
        }
      }
    }
  }
  #undef ISSUE
}

// ---------------- Kernel 6: combine + residual ----------------
__global__ __launch_bounds__(256) void k_combine(
    const float* __restrict__ x, const float* __restrict__ eo,
    const int* __restrict__ slot_of, float* __restrict__ out)
{
  const int t = blockIdx.x, tid = threadIdx.x;
  const int s0 = slot_of[t*2], s1 = slot_of[t*2+1];
  float4 xv = reinterpret_cast<const float4*>(x)[t*256 + tid];
  float4 a  = reinterpret_cast<const float4*>(eo)[s0*256 + tid];
  float4 b  = reinterpret_cast<const float4*>(eo)[s1*256 + tid];
  float4 ov;
  ov.x = xv.x + a.x + b.x;
  ov.y = xv.y + a.y + b.y;
  ov.z = xv.z + a.z + b.z;
  ov.w = xv.w + a.w + b.w;
  reinterpret_cast<float4*>(out)[t*256 + tid] = ov;
}

extern "C" void kernel_launch(void* const* d_in, const int* in_sizes, int n_in,
                              void* d_out, int out_size, void* d_ws, size_t ws_size,
                              hipStream_t stream)
{
  const float* x    = (const float*)d_in[0];
  const float* rmsw = (const float*)d_in[1];
  const float* gw   = (const float*)d_in[2];
  const float* w1   = (const float*)d_in[3];
  const float* w2   = (const float*)d_in[4];
  const float* w3   = (const float*)d_in[5];
  float* out = (float*)d_out;

  char* ws = (char*)d_ws;
  size_t o = 0;
  auto alloc = [&](size_t bytes) -> void* {
    void* p = ws + o;
    o += (bytes + 255) & ~(size_t)255;
    return p;
  };
  unsigned short* h_bf   = (unsigned short*)alloc((size_t)T_TOK*HDIM*2);
  int*   topk_i          = (int*)  alloc(T_TOK*2*4);
  float* topk_w          = (float*)alloc(T_TOK*2*4);
  int*   counters        = (int*)  alloc(64*4);   // count[8], cursor[8], offset[8]
  int*   jobs            = (int*)  alloc(NJOBS*4);
  int*   token_of_row    = (int*)  alloc(NROWS*4);
  float* wrow            = (float*)alloc(NROWS*4);
  int*   slot_of         = (int*)  alloc(T_TOK*2*4);
  unsigned short* act    = (unsigned short*)alloc((size_t)NROWS*IDIM*2);
  float* eo              = (float*)alloc((size_t)NROWS*HDIM*4);
  int* count  = counters;
  int* cursor = counters + 8;
  int* offset = counters + 16;

  // bf16 weight buffers. 2 always needed; 3rd enables hiding the w2
  // conversion inside mlp_in.
  bool have3 = (ws_size >= o + (size_t)3*WELEM*2);
  unsigned short* w1bf = (unsigned short*)(ws + o);
  unsigned short* w3bf = w1bf + WELEM;
  unsigned short* w2bf = have3 ? (w3bf + WELEM) : w1bf;   // alias if tight

  hipMemsetAsync(counters, 0, 64*4, stream);
  k_rms_router<<<T_TOK, 256, 0, stream>>>(x, rmsw, gw, h_bf, topk_i, topk_w, count);
  k_scan<<<1, 64, 0, stream>>>(count, offset, jobs);
  k_scatter<<<(T_TOK+255)/256, 256, 0, stream>>>(topk_i, topk_w, offset, cursor,
                                                 token_of_row, wrow, slot_of);
  k_cvt13<<<1792, 256, 0, stream>>>((const float4*)w1, (const float4*)w3,
                                    (uint2*)w1bf, (uint2*)w3bf);
  k_mlp_in<<<NJOBS*56 + (have3 ? CVTB : 0), 256, 0, stream>>>(
      h_bf, w1bf, w3bf, token_of_row, count, offset, jobs, act,
      (const float4*)w2, have3 ? (uint2*)w2bf : (uint2*)nullptr);
  if (!have3)
    k_cvt<<<2048, 256, 0, stream>>>((const float4*)w2, (uint2*)w2bf, WELEM/4);
  k_mlp_out<<<NJOBS*16, 256, 0, stream>>>(act, w2bf, wrow, count, offset, jobs, eo);
  k_combine<<<T_TOK, 256, 0, stream>>>(x, eo, slot_of, out);
}

// Round 15
// 330.966 us; speedup vs baseline: 1.0051x; 1.0051x over previous
//
#include <hip/hip_runtime.h>
#include <hip/hip_bf16.h>
#include <stdint.h>

#define T_TOK 2048
#define HDIM  1024
#define IDIM  3584
#define NEXP  8
#define NROWS 4096      // T_TOK * TOP_K
#define WELEM 29360128  // elements per weight tensor (8*3584*1024)
#define NJOBS 40        // max (expert,rowtile) jobs: 32 + 7 rounding
#define CVTB  512       // cvt-w2 blocks appended to mlp_in grid

typedef __attribute__((ext_vector_type(8))) short bf16x8;
typedef __attribute__((ext_vector_type(4))) float f32x4;

typedef __attribute__((address_space(3))) unsigned lds_u32;
typedef const __attribute__((address_space(1))) unsigned glb_u32;

#define MFMA16 __builtin_amdgcn_mfma_f32_16x16x32_bf16

__device__ __forceinline__ unsigned short f2bf(float f){
  union { float f; unsigned u; } v; v.f = f;
  unsigned r = v.u + 0x7FFFu + ((v.u >> 16) & 1u);   // RNE
  return (unsigned short)(r >> 16);
}
__device__ __forceinline__ unsigned cvt2(float a, float b){
  __hip_bfloat162 h = __float22bfloat162_rn(float2{a, b});
  return *reinterpret_cast<unsigned*>(&h);
}

// ---------------- Kernel 1: RMSNorm + router ----------------
__global__ __launch_bounds__(256) void k_rms_router(
    const float* __restrict__ x, const float* __restrict__ rmsw,
    const float* __restrict__ gw, unsigned short* __restrict__ h_bf,
    int* __restrict__ topk_i, float* __restrict__ topk_w, int* __restrict__ count)
{
  const int t = blockIdx.x, tid = threadIdx.x;
  const int lane = tid & 63, wid = tid >> 6;
  float4 x4 = reinterpret_cast<const float4*>(x)[t*256 + tid];
  float ss = x4.x*x4.x + x4.y*x4.y + x4.z*x4.z + x4.w*x4.w;
  #pragma unroll
  for (int o = 32; o >= 1; o >>= 1) ss += __shfl_xor(ss, o);
  __shared__ float sred[4];
  __shared__ float slog[32];
  if (lane == 0) sred[wid] = ss;
  __syncthreads();
  float inv = rsqrtf((sred[0]+sred[1]+sred[2]+sred[3]) * (1.0f/HDIM) + 1e-6f);
  float4 w4 = reinterpret_cast<const float4*>(rmsw)[tid];
  float h0 = x4.x*inv*w4.x, h1 = x4.y*inv*w4.y, h2 = x4.z*inv*w4.z, h3 = x4.w*inv*w4.w;
  ushort4 hb; hb.x = f2bf(h0); hb.y = f2bf(h1); hb.z = f2bf(h2); hb.w = f2bf(h3);
  reinterpret_cast<ushort4*>(h_bf)[t*256 + tid] = hb;
  #pragma unroll
  for (int e = 0; e < NEXP; e++){
    float4 g4 = reinterpret_cast<const float4*>(gw)[e*256 + tid];
    float v = h0*g4.x + h1*g4.y + h2*g4.z + h3*g4.w;
    #pragma unroll
    for (int o = 32; o >= 1; o >>= 1) v += __shfl_xor(v, o);
    if (lane == 0) slog[e*4 + wid] = v;
  }
  __syncthreads();
  if (tid == 0){
    float lg[NEXP];
    #pragma unroll
    for (int e = 0; e < NEXP; e++) lg[e] = slog[e*4]+slog[e*4+1]+slog[e*4+2]+slog[e*4+3];
    int i0 = 0;
    for (int e = 1; e < NEXP; e++) if (lg[e] > lg[i0]) i0 = e;   // ties -> lowest index
    int i1 = -1;
    for (int e = 0; e < NEXP; e++){ if (e == i0) continue; if (i1 < 0 || lg[e] > lg[i1]) i1 = e; }
    float m  = fmaxf(lg[i0], lg[i1]);
    float e0 = expf(lg[i0]-m), e1 = expf(lg[i1]-m);
    float s  = e0 + e1;
    topk_i[t*2] = i0; topk_i[t*2+1] = i1;
    topk_w[t*2] = e0/s; topk_w[t*2+1] = e1/s;
    atomicAdd(&count[i0], 1); atomicAdd(&count[i1], 1);
  }
}

// ---------------- Kernel 1b: streaming cvt of w1+w3 ----------------
// Grid-stride with x4 iteration unroll: lane-consecutive float4 per
// instruction (perfect coalescing), 8 independent loads in flight.
// 1792*256 threads x 16 float4/thread == WELEM/4 exactly.
__global__ __launch_bounds__(256) void k_cvt13(
    const float4* __restrict__ a, const float4* __restrict__ b,
    uint2* __restrict__ da, uint2* __restrict__ db)
{
  const size_t S = (size_t)1792*256;
  size_t i = (size_t)blockIdx.x*256 + threadIdx.x;
  #pragma unroll 1
  for (int o = 0; o < 4; o++){
    float4 va0 = a[i], va1 = a[i+S], va2 = a[i+2*S], va3 = a[i+3*S];
    float4 vb0 = b[i], vb1 = b[i+S], vb2 = b[i+2*S], vb3 = b[i+3*S];
    da[i]     = make_uint2(cvt2(va0.x,va0.y), cvt2(va0.z,va0.w));
    da[i+S]   = make_uint2(cvt2(va1.x,va1.y), cvt2(va1.z,va1.w));
    da[i+2*S] = make_uint2(cvt2(va2.x,va2.y), cvt2(va2.z,va2.w));
    da[i+3*S] = make_uint2(cvt2(va3.x,va3.y), cvt2(va3.z,va3.w));
    db[i]     = make_uint2(cvt2(vb0.x,vb0.y), cvt2(vb0.z,vb0.w));
    db[i+S]   = make_uint2(cvt2(vb1.x,vb1.y), cvt2(vb1.z,vb1.w));
    db[i+2*S] = make_uint2(cvt2(vb2.x,vb2.y), cvt2(vb2.z,vb2.w));
    db[i+3*S] = make_uint2(cvt2(vb3.x,vb3.y), cvt2(vb3.z,vb3.w));
    i += 4*S;
  }
}

// ---------------- Kernel 2: offsets + job list ----------------
__global__ void k_scan(const int* __restrict__ count, int* __restrict__ offset,
                       int* __restrict__ jobs){
  if (threadIdx.x == 0){
    int o = 0, L = 0;
    for (int e = 0; e < NEXP; e++){
      offset[e] = o;
      int nrt = (count[e] + 127) >> 7;
      for (int r = 0; r < nrt && L < NJOBS; r++) jobs[L++] = (e << 8) | r;
      o += count[e];
    }
    for (; L < NJOBS; L++) jobs[L] = -1;
  }
}

// ---------------- Kernel 3: scatter ----------------
__global__ __launch_bounds__(256) void k_scatter(
    const int* __restrict__ topk_i, const float* __restrict__ topk_w,
    const int* __restrict__ offset, int* __restrict__ cursor,
    int* __restrict__ token_of_row, float* __restrict__ wrow, int* __restrict__ slot_of)
{
  int t = blockIdx.x*256 + threadIdx.x;
  if (t >= T_TOK) return;
  #pragma unroll
  for (int k = 0; k < 2; k++){
    int e = topk_i[t*2+k];
    int pos = atomicAdd(&cursor[e], 1);
    int row = offset[e] + pos;
    token_of_row[row] = t;
    wrow[row] = topk_w[t*2+k];
    slot_of[t*2+k] = row;
  }
}

// ---------------- Kernel: fp32 -> bf16 (standalone, fallback path) ----------------
__global__ __launch_bounds__(256) void k_cvt(
    const float4* __restrict__ src, uint2* __restrict__ dst, int n4)
{
  int stride = gridDim.x * blockDim.x;
  for (int i = blockIdx.x*blockDim.x + threadIdx.x; i < n4; i += stride){
    float4 v = src[i];
    dst[i] = make_uint2(cvt2(v.x, v.y), cvt2(v.z, v.w));
  }
}

// =====================================================================
// Kernel 4: fused w1/w3 GEMM + SwiGLU  (R9-exact core, work-list grid)
// Tile 128 rows x 64 cols, BK=64, 256 thr / 4 waves (2x2), wave 64x32.
// d = t*56 + p  (p = panel 0..55, t = job 0..39); all consumers of panel p
// land on XCD p%8 (56 == 0 mod 8). Blocks d >= 2240 stream-convert w2.
// =====================================================================
__global__ __launch_bounds__(256, 3) void k_mlp_in(
    const unsigned short* __restrict__ h_bf, const unsigned short* __restrict__ w1bf,
    const unsigned short* __restrict__ w3bf, const int* __restrict__ token_of_row,
    const int* __restrict__ count, const int* __restrict__ offset,
    const int* __restrict__ jobs, unsigned short* __restrict__ act,
    const float4* __restrict__ w2s, uint2* __restrict__ w2d)
{
  const int d = blockIdx.x;
  const int tid = threadIdx.x;
  if (d >= NJOBS*56){
    // ---- cvt-w2 role (only present when 3 bf16 buffers fit in ws) ----
    if (w2d){
      int i0 = (d - NJOBS*56)*256 + tid;
      for (int i = i0; i < WELEM/4; i += CVTB*256){
        float4 v = w2s[i];
        w2d[i] = make_uint2(cvt2(v.x, v.y), cvt2(v.z, v.w));
      }
    }
    return;
  }
  const int p = d % 56;
  const int t = d / 56;
  const int job = jobs[t];
  if (job < 0) return;
  const int e = job >> 8, rt = job & 255;
  const int cnt = count[e];
  const int off = offset[e], row0 = off + rt*128, rend = off + cnt;
  const int col0 = p * 64;
  const int lane = tid & 63, wid = tid >> 6;
  const int wave_r = wid >> 1, wave_c = wid & 1;

  __shared__ __align__(16) char sA [16384];  // 128 rows x 64 k bf16 (swizzled)
  __shared__ __align__(16) char sB1[8192];   // 64 cols x 64 k bf16
  __shared__ __align__(16) char sB2[8192];

  const int srow = tid >> 3;                // 0..31
  const int sg   = (tid & 7) ^ (srow & 7);  // pre-swizzled logical k-chunk

  const unsigned short* aptr[4];
  #pragma unroll
  for (int j = 0; j < 4; j++){
    int tok = token_of_row[min(row0 + srow + 32*j, NROWS-1)];
    aptr[j] = h_bf + (size_t)tok*HDIM + sg*8;
  }
  const unsigned short* b1ptr[2];
  const unsigned short* b3ptr[2];
  #pragma unroll
  for (int j = 0; j < 2; j++){
    int col = col0 + srow + 32*j;
    b1ptr[j] = w1bf + (size_t)(e*IDIM + col)*HDIM + sg*8;
    b3ptr[j] = w3bf + (size_t)(e*IDIM + col)*HDIM + sg*8;
  }

  #define ISSUE(kk) {                                                                \
    _Pragma("unroll")                                                                \
    for (int j = 0; j < 4; j++)                                                      \
      __builtin_amdgcn_global_load_lds((glb_u32*)(const void*)(aptr[j] + (kk)*64),   \
          (lds_u32*)(void*)(sA + j*4096 + tid*16), 16, 0, 0);                        \
    _Pragma("unroll")                                                                \
    for (int j = 0; j < 2; j++){                                                     \
      __builtin_amdgcn_global_load_lds((glb_u32*)(const void*)(b1ptr[j] + (kk)*64),  \
          (lds_u32*)(void*)(sB1 + j*4096 + tid*16), 16, 0, 0);                       \
      __builtin_amdgcn_global_load_lds((glb_u32*)(const void*)(b3ptr[j] + (kk)*64),  \
          (lds_u32*)(void*)(sB2 + j*4096 + tid*16), 16, 0, 0);                       \
    } }

  f32x4 acc1[4][2], acc3[4][2];
  #pragma unroll
  for (int m = 0; m < 4; m++)
    #pragma unroll
    for (int n = 0; n < 2; n++){
      acc1[m][n] = (f32x4){0.f,0.f,0.f,0.f};
      acc3[m][n] = (f32x4){0.f,0.f,0.f,0.f};
    }

  for (int kk = 0; kk < HDIM/64; kk++){
    ISSUE(kk);
    __syncthreads();          // drains vmcnt: tile kk ready (m97 pattern)
    #pragma unroll
    for (int ki = 0; ki < 2; ki++){
      bf16x8 af[4];
      #pragma unroll
      for (int m = 0; m < 4; m++){
        int row = wave_r*64 + m*16 + (lane & 15);
        int slot = ki*4 + (lane >> 4);
        af[m] = *reinterpret_cast<const bf16x8*>(sA + row*128 + ((slot ^ (row&7))<<4));
      }
      #pragma unroll
      for (int n = 0; n < 2; n++){
        int col = wave_c*32 + n*16 + (lane & 15);
        int slot = ki*4 + (lane >> 4);
        bf16x8 b1 = *reinterpret_cast<const bf16x8*>(sB1 + col*128 + ((slot ^ (col&7))<<4));
        bf16x8 b2 = *reinterpret_cast<const bf16x8*>(sB2 + col*128 + ((slot ^ (col&7))<<4));
        #pragma unroll
        for (int m = 0; m < 4; m++){
          acc1[m][n] = MFMA16(af[m], b1, acc1[m][n], 0,0,0);
          acc3[m][n] = MFMA16(af[m], b2, acc3[m][n], 0,0,0);
        }
      }
    }
    __syncthreads();          // reads done before next overwrite
  }

  const int lcol = lane & 15, lrow4 = (lane >> 4) * 4;
  #pragma unroll
  for (int m = 0; m < 4; m++){
    #pragma unroll
    for (int n = 0; n < 2; n++){
      int gcol = col0 + wave_c*32 + n*16 + lcol;
      #pragma unroll
      for (int r = 0; r < 4; r++){
        int grow = row0 + wave_r*64 + m*16 + lrow4 + r;
        if (grow < rend){
          float a = acc1[m][n][r], g = acc3[m][n][r];
          float sig = 1.0f / (1.0f + __expf(-a));
          act[(size_t)grow*IDIM + gcol] = f2bf(a * sig * g);
        }
      }
    }
  }
  #undef ISSUE
}

// =====================================================================
// Kernel 5: w2 GEMM, BK=128 (28 K-steps), 16-slot XOR swizzle.
// Tile 128 rows x 64 cols, 256 thr / 4 waves (2x2), wave 64x32.
// LDS 48KB -> 3 blocks/CU. d = t*16 + p  (panel-XCD pin: 16 == 0 mod 8).
// =====================================================================
__global__ __launch_bounds__(256, 3) void k_mlp_out(
    const unsigned short* __restrict__ act, const unsigned short* __restrict__ w2bf,
    const float* __restrict__ wrow, const int* __restrict__ count,
    const int* __restrict__ offset, const int* __restrict__ jobs,
    float* __restrict__ eo)
{
  const int d = blockIdx.x;
  const int p = d & 15;
  const int t = d >> 4;
  const int job = jobs[t];
  if (job < 0) return;
  const int e = job >> 8, rt = job & 255;
  const int cnt = count[e];
  const int off = offset[e], row0 = off + rt*128, rend = off + cnt;
  const int col0 = p * 64;
  const int tid = threadIdx.x, lane = tid & 63, wid = tid >> 6;
  const int wave_r = wid >> 1, wave_c = wid & 1;

  __shared__ __align__(16) char sA[32768];   // 128 rows x 128 k bf16 (256B rows, swizzled)
  __shared__ __align__(16) char sB[16384];   // 64 cols x 128 k bf16

  const int sr16 = tid >> 4;            // 0..15
  const int sg   = (tid & 15) ^ sr16;   // pre-swizzled logical 16B slot

  const unsigned short* aptr[8];
  #pragma unroll
  for (int j = 0; j < 8; j++){
    int r = min(row0 + j*16 + sr16, NROWS-1);
    aptr[j] = act + (size_t)r*IDIM + sg*8;
  }
  const unsigned short* bptr[4];
  #pragma unroll
  for (int j = 0; j < 4; j++){
    int col = col0 + j*16 + sr16;
    bptr[j] = w2bf + (size_t)(e*HDIM + col)*IDIM + sg*8;
  }

  #define ISSUE(kk) {                                                                \
    _Pragma("unroll")                                                                \
    for (int j = 0; j < 8; j++)                                                      \
      __builtin_amdgcn_global_load_lds((glb_u32*)(const void*)(aptr[j] + (kk)*128),  \
          (lds_u32*)(void*)(sA + j*4096 + tid*16), 16, 0, 0);                        \
    _Pragma("unroll")                                                                \
    for (int j = 0; j < 4; j++)                                                      \
      __builtin_amdgcn_global_load_lds((glb_u32*)(const void*)(bptr[j] + (kk)*128),  \
          (lds_u32*)(void*)(sB + j*4096 + tid*16), 16, 0, 0); }

  f32x4 acc[4][2];
  #pragma unroll
  for (int m = 0; m < 4; m++)
    #pragma unroll
    for (int n = 0; n < 2; n++) acc[m][n] = (f32x4){0.f,0.f,0.f,0.f};

  for (int kk = 0; kk < IDIM/128; kk++){
    ISSUE(kk);
    __syncthreads();
    #pragma unroll
    for (int ki = 0; ki < 4; ki++){
      bf16x8 af[4];
      #pragma unroll
      for (int m = 0; m < 4; m++){
        int row = wave_r*64 + m*16 + (lane & 15);
        int slot = ki*4 + (lane >> 4);
        af[m] = *reinterpret_cast<const bf16x8*>(sA + row*256 + ((slot ^ (row&15))<<4));
      }
      #pragma unroll
      for (int n = 0; n < 2; n++){
        int col = wave_c*32 + n*16 + (lane & 15);
        int slot = ki*4 + (lane >> 4);
        bf16x8 fb = *reinterpret_cast<const bf16x8*>(sB + col*256 + ((slot ^ (col&15))<<4));
        #pragma unroll
        for (int m = 0; m < 4; m++)
          acc[m][n] = MFMA16(af[m], fb, acc[m][n], 0,0,0);
      }
    }
    __syncthreads();
  }

  const int lcol = lane & 15, lrow4 = (lane >> 4) * 4;
  #pragma unroll
  for (int m = 0; m < 4; m++){
    #pragma unroll
    for (int n = 0; n < 2; n++){
      int gcol = col0 + wave_c*32 + n*16 + lcol;
      #pragma unroll
      for (int r = 0; r < 4; r++){
        int grow = row0 + wave_r*64 + m*16 + lrow4 + r;
        if (grow < rend){
          eo[(size_t)grow*HDIM + gcol] = acc[m][n][r] * wrow[grow];
        }
      }
    }
  }
  #undef ISSUE
}

// ---------------- Kernel 6: combine + residual ----------------
__global__ __launch_bounds__(256) void k_combine(
    const float* __restrict__ x, const float* __restrict__ eo,
    const int* __restrict__ slot_of, float* __restrict__ out)
{
  const int t = blockIdx.x, tid = threadIdx.x;
  const int s0 = slot_of[t*2], s1 = slot_of[t*2+1];
  float4 xv = reinterpret_cast<const float4*>(x)[t*256 + tid];
  float4 a  = reinterpret_cast<const float4*>(eo)[s0*256 + tid];
  float4 b  = reinterpret_cast<const float4*>(eo)[s1*256 + tid];
  float4 ov;
  ov.x = xv.x + a.x + b.x;
  ov.y = xv.y + a.y + b.y;
  ov.z = xv.z + a.z + b.z;
  ov.w = xv.w + a.w + b.w;
  reinterpret_cast<float4*>(out)[t*256 + tid] = ov;
}

extern "C" void kernel_launch(void* const* d_in, const int* in_sizes, int n_in,
                              void* d_out, int out_size, void* d_ws, size_t ws_size,
                              hipStream_t stream)
{
  const float* x    = (const float*)d_in[0];
  const float* rmsw = (const float*)d_in[1];
  const float* gw   = (const float*)d_in[2];
  const float* w1   = (const float*)d_in[3];
  const float* w2   = (const float*)d_in[4];
  const float* w3   = (const float*)d_in[5];
  float* out = (float*)d_out;

  char* ws = (char*)d_ws;
  size_t o = 0;
  auto alloc = [&](size_t bytes) -> void* {
    void* p = ws + o;
    o += (bytes + 255) & ~(size_t)255;
    return p;
  };
  unsigned short* h_bf   = (unsigned short*)alloc((size_t)T_TOK*HDIM*2);
  int*   topk_i          = (int*)  alloc(T_TOK*2*4);
  float* topk_w          = (float*)alloc(T_TOK*2*4);
  int*   counters        = (int*)  alloc(64*4);   // count[8], cursor[8], offset[8]
  int*   jobs            = (int*)  alloc(NJOBS*4);
  int*   token_of_row    = (int*)  alloc(NROWS*4);
  float* wrow            = (float*)alloc(NROWS*4);
  int*   slot_of         = (int*)  alloc(T_TOK*2*4);
  unsigned short* act    = (unsigned short*)alloc((size_t)NROWS*IDIM*2);
  float* eo              = (float*)alloc((size_t)NROWS*HDIM*4);
  int* count  = counters;
  int* cursor = counters + 8;
  int* offset = counters + 16;

  // bf16 weight buffers. 2 always needed; 3rd enables hiding the w2
  // conversion inside mlp_in.
  bool have3 = (ws_size >= o + (size_t)3*WELEM*2);
  unsigned short* w1bf = (unsigned short*)(ws + o);
  unsigned short* w3bf = w1bf + WELEM;
  unsigned short* w2bf = have3 ? (w3bf + WELEM) : w1bf;   // alias if tight

  hipMemsetAsync(counters, 0, 64*4, stream);
  k_rms_router<<<T_TOK, 256, 0, stream>>>(x, rmsw, gw, h_bf, topk_i, topk_w, count);
  k_scan<<<1, 64, 0, stream>>>(count, offset, jobs);
  k_scatter<<<(T_TOK+255)/256, 256, 0, stream>>>(topk_i, topk_w, offset, cursor,
                                                 token_of_row, wrow, slot_of);
  k_cvt13<<<1792, 256, 0, stream>>>((const float4*)w1, (const float4*)w3,
                                    (uint2*)w1bf, (uint2*)w3bf);
  k_mlp_in<<<NJOBS*56 + (have3 ? CVTB : 0), 256, 0, stream>>>(
      h_bf, w1bf, w3bf, token_of_row, count, offset, jobs, act,
      (const float4*)w2, have3 ? (uint2*)w2bf : (uint2*)nullptr);
  if (!have3)
    k_cvt<<<2048, 256, 0, stream>>>((const float4*)w2, (uint2*)w2bf, WELEM/4);
  k_mlp_out<<<NJOBS*16, 256, 0, stream>>>(act, w2bf, wrow, count, offset, jobs, eo);
  k_combine<<<T_TOK, 256, 0, stream>>>(x, eo, slot_of, out);
}

// Round 16
// 295.382 us; speedup vs baseline: 1.1262x; 1.1205x over previous
//
#include <hip/hip_runtime.h>
#include <hip/hip_bf16.h>
#include <stdint.h>

#define T_TOK 2048
#define HDIM  1024
#define IDIM  3584
#define NEXP  8
#define NROWS 4096      // T_TOK * TOP_K
#define WELEM 29360128  // elements per weight tensor (8*3584*1024)
#define NJOBS 40        // max (expert,rowtile) jobs: 32 + 7 rounding
#define CVTB  512       // cvt-w2 blocks appended to mlp_in grid

typedef __attribute__((ext_vector_type(8))) short bf16x8;
typedef __attribute__((ext_vector_type(4))) float f32x4;

typedef __attribute__((address_space(3))) unsigned lds_u32;
typedef const __attribute__((address_space(1))) unsigned glb_u32;

#define MFMA16 __builtin_amdgcn_mfma_f32_16x16x32_bf16

__device__ __forceinline__ unsigned short f2bf(float f){
  union { float f; unsigned u; } v; v.f = f;
  unsigned r = v.u + 0x7FFFu + ((v.u >> 16) & 1u);   // RNE
  return (unsigned short)(r >> 16);
}
__device__ __forceinline__ unsigned cvt2(float a, float b){
  __hip_bfloat162 h = __float22bfloat162_rn(float2{a, b});
  return *reinterpret_cast<unsigned*>(&h);
}
__device__ __forceinline__ bf16x8 pack8(float4 lo, float4 hi){
  union { __hip_bfloat162 b2[4]; bf16x8 v; } u;
  u.b2[0] = __float22bfloat162_rn(float2{lo.x, lo.y});
  u.b2[1] = __float22bfloat162_rn(float2{lo.z, lo.w});
  u.b2[2] = __float22bfloat162_rn(float2{hi.x, hi.y});
  u.b2[3] = __float22bfloat162_rn(float2{hi.z, hi.w});
  return u.v;
}

// ---------------- Kernel 1: RMSNorm + router ----------------
__global__ __launch_bounds__(256) void k_rms_router(
    const float* __restrict__ x, const float* __restrict__ rmsw,
    const float* __restrict__ gw, unsigned short* __restrict__ h_bf,
    int* __restrict__ topk_i, float* __restrict__ topk_w, int* __restrict__ count)
{
  const int t = blockIdx.x, tid = threadIdx.x;
  const int lane = tid & 63, wid = tid >> 6;
  float4 x4 = reinterpret_cast<const float4*>(x)[t*256 + tid];
  float ss = x4.x*x4.x + x4.y*x4.y + x4.z*x4.z + x4.w*x4.w;
  #pragma unroll
  for (int o = 32; o >= 1; o >>= 1) ss += __shfl_xor(ss, o);
  __shared__ float sred[4];
  __shared__ float slog[32];
  if (lane == 0) sred[wid] = ss;
  __syncthreads();
  float inv = rsqrtf((sred[0]+sred[1]+sred[2]+sred[3]) * (1.0f/HDIM) + 1e-6f);
  float4 w4 = reinterpret_cast<const float4*>(rmsw)[tid];
  float h0 = x4.x*inv*w4.x, h1 = x4.y*inv*w4.y, h2 = x4.z*inv*w4.z, h3 = x4.w*inv*w4.w;
  ushort4 hb; hb.x = f2bf(h0); hb.y = f2bf(h1); hb.z = f2bf(h2); hb.w = f2bf(h3);
  reinterpret_cast<ushort4*>(h_bf)[t*256 + tid] = hb;
  #pragma unroll
  for (int e = 0; e < NEXP; e++){
    float4 g4 = reinterpret_cast<const float4*>(gw)[e*256 + tid];
    float v = h0*g4.x + h1*g4.y + h2*g4.z + h3*g4.w;
    #pragma unroll
    for (int o = 32; o >= 1; o >>= 1) v += __shfl_xor(v, o);
    if (lane == 0) slog[e*4 + wid] = v;
  }
  __syncthreads();
  if (tid == 0){
    float lg[NEXP];
    #pragma unroll
    for (int e = 0; e < NEXP; e++) lg[e] = slog[e*4]+slog[e*4+1]+slog[e*4+2]+slog[e*4+3];
    int i0 = 0;
    for (int e = 1; e < NEXP; e++) if (lg[e] > lg[i0]) i0 = e;   // ties -> lowest index
    int i1 = -1;
    for (int e = 0; e < NEXP; e++){ if (e == i0) continue; if (i1 < 0 || lg[e] > lg[i1]) i1 = e; }
    float m  = fmaxf(lg[i0], lg[i1]);
    float e0 = expf(lg[i0]-m), e1 = expf(lg[i1]-m);
    float s  = e0 + e1;
    topk_i[t*2] = i0; topk_i[t*2+1] = i1;
    topk_w[t*2] = e0/s; topk_w[t*2+1] = e1/s;
    atomicAdd(&count[i0], 1); atomicAdd(&count[i1], 1);
  }
}

// ---------------- Kernel 2: offsets + job list ----------------
__global__ void k_scan(const int* __restrict__ count, int* __restrict__ offset,
                       int* __restrict__ jobs){
  if (threadIdx.x == 0){
    int o = 0, L = 0;
    for (int e = 0; e < NEXP; e++){
      offset[e] = o;
      int nrt = (count[e] + 127) >> 7;
      for (int r = 0; r < nrt && L < NJOBS; r++) jobs[L++] = (e << 8) | r;
      o += count[e];
    }
    for (; L < NJOBS; L++) jobs[L] = -1;
  }
}

// ---------------- Kernel 3: scatter ----------------
__global__ __launch_bounds__(256) void k_scatter(
    const int* __restrict__ topk_i, const float* __restrict__ topk_w,
    const int* __restrict__ offset, int* __restrict__ cursor,
    int* __restrict__ token_of_row, float* __restrict__ wrow, int* __restrict__ slot_of)
{
  int t = blockIdx.x*256 + threadIdx.x;
  if (t >= T_TOK) return;
  #pragma unroll
  for (int k = 0; k < 2; k++){
    int e = topk_i[t*2+k];
    int pos = atomicAdd(&cursor[e], 1);
    int row = offset[e] + pos;
    token_of_row[row] = t;
    wrow[row] = topk_w[t*2+k];
    slot_of[t*2+k] = row;
  }
}

// ---------------- Kernel: fp32 -> bf16 (standalone, fallback path) ----------------
__global__ __launch_bounds__(256) void k_cvt(
    const float4* __restrict__ src, uint2* __restrict__ dst, int n4)
{
  int stride = gridDim.x * blockDim.x;
  for (int i = blockIdx.x*blockDim.x + threadIdx.x; i < n4; i += stride){
    float4 v = src[i];
    dst[i] = make_uint2(cvt2(v.x, v.y), cvt2(v.z, v.w));
  }
}

// =====================================================================
// Kernel 4: fused w1/w3 GEMM + SwiGLU — fp32 B staged RAW via
// global_load_lds (NO separate cvt pass), bf16-converted at LDS-read.
// Tile 128 rows x 64 cols, BK=64, 256 thr / 4 waves (2x2), wave 64x32.
// A (bf16): R9 staging, phys slot = slot^(row&7).
// B (fp32): 64 cols x 256B rows; thread t stages cols (t>>4)+16j, phys
//   slot t&15 holding logical (t&15)^((t>>4)&15); read phys = l^(c&15).
// d = t*56 + p: consumers of panel p share XCD p%8 (fp32 panel L2-reuse).
// Blocks d >= NJOBS*56 stream-convert w2 (hidden behind the GEMM).
// =====================================================================
__global__ __launch_bounds__(256, 3) void k_mlp_in(
    const unsigned short* __restrict__ h_bf, const float* __restrict__ w1,
    const float* __restrict__ w3, const int* __restrict__ token_of_row,
    const int* __restrict__ count, const int* __restrict__ offset,
    const int* __restrict__ jobs, unsigned short* __restrict__ act,
    const float4* __restrict__ w2s, uint2* __restrict__ w2d)
{
  const int d = blockIdx.x;
  const int tid = threadIdx.x;
  if (d >= NJOBS*56){
    // ---- cvt-w2 role ----
    if (w2d){
      int i0 = (d - NJOBS*56)*256 + tid;
      for (int i = i0; i < WELEM/4; i += CVTB*256){
        float4 v = w2s[i];
        w2d[i] = make_uint2(cvt2(v.x, v.y), cvt2(v.z, v.w));
      }
    }
    return;
  }
  const int p = d % 56;
  const int t = d / 56;
  const int job = jobs[t];
  if (job < 0) return;
  const int e = job >> 8, rt = job & 255;
  const int cnt = count[e];
  const int off = offset[e], row0 = off + rt*128, rend = off + cnt;
  const int col0 = p * 64;
  const int lane = tid & 63, wid = tid >> 6;
  const int wave_r = wid >> 1, wave_c = wid & 1;

  __shared__ __align__(16) char sA [16384];   // 128 rows x 64 k bf16 (swizzled)
  __shared__ __align__(16) char sB1[16384];   // 64 cols x 64 k fp32 (swizzled)
  __shared__ __align__(16) char sB3[16384];

  // ---- A staging (R9-proven) ----
  const int srow = tid >> 3;
  const int sg   = (tid & 7) ^ (srow & 7);
  const unsigned short* aptr[4];
  #pragma unroll
  for (int j = 0; j < 4; j++){
    int tok = token_of_row[min(row0 + srow + 32*j, NROWS-1)];
    aptr[j] = h_bf + (size_t)tok*HDIM + sg*8;
  }
  // ---- B staging: fp32, pre-swizzled source (R12-proven) ----
  const int bl = (tid & 15) ^ ((tid >> 4) & 15);   // logical 16B slot staged
  const float* b1base = w1 + ((size_t)e*IDIM + col0 + (tid >> 4))*HDIM + bl*4;
  const float* b3base = w3 + ((size_t)e*IDIM + col0 + (tid >> 4))*HDIM + bl*4;

  #define ISSUE(kk) {                                                                \
    _Pragma("unroll")                                                                \
    for (int j = 0; j < 4; j++)                                                      \
      __builtin_amdgcn_global_load_lds((glb_u32*)(const void*)(aptr[j] + (kk)*64),   \
          (lds_u32*)(void*)(sA + j*4096 + tid*16), 16, 0, 0);                        \
    _Pragma("unroll")                                                                \
    for (int j = 0; j < 4; j++){                                                     \
      __builtin_amdgcn_global_load_lds(                                              \
          (glb_u32*)(const void*)(b1base + (size_t)j*16*HDIM + (kk)*64),             \
          (lds_u32*)(void*)(sB1 + j*4096 + tid*16), 16, 0, 0);                       \
      __builtin_amdgcn_global_load_lds(                                              \
          (glb_u32*)(const void*)(b3base + (size_t)j*16*HDIM + (kk)*64),             \
          (lds_u32*)(void*)(sB3 + j*4096 + tid*16), 16, 0, 0);                       \
    } }

  f32x4 acc1[4][2], acc3[4][2];
  #pragma unroll
  for (int m = 0; m < 4; m++)
    #pragma unroll
    for (int n = 0; n < 2; n++){
      acc1[m][n] = (f32x4){0.f,0.f,0.f,0.f};
      acc3[m][n] = (f32x4){0.f,0.f,0.f,0.f};
    }

  for (int kk = 0; kk < HDIM/64; kk++){
    ISSUE(kk);
    __syncthreads();          // drains vmcnt: tile kk ready (m97 pattern)
    #pragma unroll
    for (int ki = 0; ki < 2; ki++){
      bf16x8 af[4];
      #pragma unroll
      for (int m = 0; m < 4; m++){
        int row = wave_r*64 + m*16 + (lane & 15);
        int slot = ki*4 + (lane >> 4);
        af[m] = *reinterpret_cast<const bf16x8*>(sA + row*128 + ((slot ^ (row&7))<<4));
      }
      #pragma unroll
      for (int n = 0; n < 2; n++){
        int c  = wave_c*32 + n*16 + (lane & 15);       // local col 0..63
        int l0 = ki*8 + (lane >> 4)*2;                 // logical 16B slot
        int p0 = (l0     ^ (c & 15)) << 4;
        int p1 = ((l0+1) ^ (c & 15)) << 4;
        float4 lo1 = *reinterpret_cast<const float4*>(sB1 + c*256 + p0);
        float4 hi1 = *reinterpret_cast<const float4*>(sB1 + c*256 + p1);
        float4 lo3 = *reinterpret_cast<const float4*>(sB3 + c*256 + p0);
        float4 hi3 = *reinterpret_cast<const float4*>(sB3 + c*256 + p1);
        bf16x8 b1 = pack8(lo1, hi1);
        bf16x8 b3 = pack8(lo3, hi3);
        #pragma unroll
        for (int m = 0; m < 4; m++){
          acc1[m][n] = MFMA16(af[m], b1, acc1[m][n], 0,0,0);
          acc3[m][n] = MFMA16(af[m], b3, acc3[m][n], 0,0,0);
        }
      }
    }
    __syncthreads();          // reads done before next overwrite
  }

  // epilogue: silu(a)*g -> bf16
  const int lcol = lane & 15, lrow4 = (lane >> 4) * 4;
  #pragma unroll
  for (int m = 0; m < 4; m++){
    #pragma unroll
    for (int n = 0; n < 2; n++){
      int gcol = col0 + wave_c*32 + n*16 + lcol;
      #pragma unroll
      for (int r = 0; r < 4; r++){
        int grow = row0 + wave_r*64 + m*16 + lrow4 + r;
        if (grow < rend){
          float a = acc1[m][n][r], g = acc3[m][n][r];
          float sig = 1.0f / (1.0f + __expf(-a));
          act[(size_t)grow*IDIM + gcol] = f2bf(a * sig * g);
        }
      }
    }
  }
  #undef ISSUE
}

// =====================================================================
// Kernel 5: w2 GEMM, BK=128 (28 K-steps), 16-slot XOR swizzle. (R13-exact)
// Tile 128 rows x 64 cols, 256 thr / 4 waves (2x2), wave 64x32.
// LDS 48KB -> 3 blocks/CU. d = t*16 + p  (panel-XCD pin: 16 == 0 mod 8).
// =====================================================================
__global__ __launch_bounds__(256, 3) void k_mlp_out(
    const unsigned short* __restrict__ act, const unsigned short* __restrict__ w2bf,
    const float* __restrict__ wrow, const int* __restrict__ count,
    const int* __restrict__ offset, const int* __restrict__ jobs,
    float* __restrict__ eo)
{
  const int d = blockIdx.x;
  const int p = d & 15;
  const int t = d >> 4;
  const int job = jobs[t];
  if (job < 0) return;
  const int e = job >> 8, rt = job & 255;
  const int cnt = count[e];
  const int off = offset[e], row0 = off + rt*128, rend = off + cnt;
  const int col0 = p * 64;
  const int tid = threadIdx.x, lane = tid & 63, wid = tid >> 6;
  const int wave_r = wid >> 1, wave_c = wid & 1;

  __shared__ __align__(16) char sA[32768];   // 128 rows x 128 k bf16 (256B rows, swizzled)
  __shared__ __align__(16) char sB[16384];   // 64 cols x 128 k bf16

  const int sr16 = tid >> 4;            // 0..15
  const int sg   = (tid & 15) ^ sr16;   // pre-swizzled logical 16B slot

  const unsigned short* aptr[8];
  #pragma unroll
  for (int j = 0; j < 8; j++){
    int r = min(row0 + j*16 + sr16, NROWS-1);
    aptr[j] = act + (size_t)r*IDIM + sg*8;
  }
  const unsigned short* bptr[4];
  #pragma unroll
  for (int j = 0; j < 4; j++){
    int col = col0 + j*16 + sr16;
    bptr[j] = w2bf + (size_t)(e*HDIM + col)*IDIM + sg*8;
  }

  #define ISSUE(kk) {                                                                \
    _Pragma("unroll")                                                                \
    for (int j = 0; j < 8; j++)                                                      \
      __builtin_amdgcn_global_load_lds((glb_u32*)(const void*)(aptr[j] + (kk)*128),  \
          (lds_u32*)(void*)(sA + j*4096 + tid*16), 16, 0, 0);                        \
    _Pragma("unroll")                                                                \
    for (int j = 0; j < 4; j++)                                                      \
      __builtin_amdgcn_global_load_lds((glb_u32*)(const void*)(bptr[j] + (kk)*128),  \
          (lds_u32*)(void*)(sB + j*4096 + tid*16), 16, 0, 0); }

  f32x4 acc[4][2];
  #pragma unroll
  for (int m = 0; m < 4; m++)
    #pragma unroll
    for (int n = 0; n < 2; n++) acc[m][n] = (f32x4){0.f,0.f,0.f,0.f};

  for (int kk = 0; kk < IDIM/128; kk++){
    ISSUE(kk);
    __syncthreads();
    #pragma unroll
    for (int ki = 0; ki < 4; ki++){
      bf16x8 af[4];
      #pragma unroll
      for (int m = 0; m < 4; m++){
        int row = wave_r*64 + m*16 + (lane & 15);
        int slot = ki*4 + (lane >> 4);
        af[m] = *reinterpret_cast<const bf16x8*>(sA + row*256 + ((slot ^ (row&15))<<4));
      }
      #pragma unroll
      for (int n = 0; n < 2; n++){
        int col = wave_c*32 + n*16 + (lane & 15);
        int slot = ki*4 + (lane >> 4);
        bf16x8 fb = *reinterpret_cast<const bf16x8*>(sB + col*256 + ((slot ^ (col&15))<<4));
        #pragma unroll
        for (int m = 0; m < 4; m++)
          acc[m][n] = MFMA16(af[m], fb, acc[m][n], 0,0,0);
      }
    }
    __syncthreads();
  }

  const int lcol = lane & 15, lrow4 = (lane >> 4) * 4;
  #pragma unroll
  for (int m = 0; m < 4; m++){
    #pragma unroll
    for (int n = 0; n < 2; n++){
      int gcol = col0 + wave_c*32 + n*16 + lcol;
      #pragma unroll
      for (int r = 0; r < 4; r++){
        int grow = row0 + wave_r*64 + m*16 + lrow4 + r;
        if (grow < rend){
          eo[(size_t)grow*HDIM + gcol] = acc[m][n][r] * wrow[grow];
        }
      }
    }
  }
  #undef ISSUE
}

// ---------------- Kernel 6: combine + residual ----------------
__global__ __launch_bounds__(256) void k_combine(
    const float* __restrict__ x, const float* __restrict__ eo,
    const int* __restrict__ slot_of, float* __restrict__ out)
{
  const int t = blockIdx.x, tid = threadIdx.x;
  const int s0 = slot_of[t*2], s1 = slot_of[t*2+1];
  float4 xv = reinterpret_cast<const float4*>(x)[t*256 + tid];
  float4 a  = reinterpret_cast<const float4*>(eo)[s0*256 + tid];
  float4 b  = reinterpret_cast<const float4*>(eo)[s1*256 + tid];
  float4 ov;
  ov.x = xv.x + a.x + b.x;
  ov.y = xv.y + a.y + b.y;
  ov.z = xv.z + a.z + b.z;
  ov.w = xv.w + a.w + b.w;
  reinterpret_cast<float4*>(out)[t*256 + tid] = ov;
}

extern "C" void kernel_launch(void* const* d_in, const int* in_sizes, int n_in,
                              void* d_out, int out_size, void* d_ws, size_t ws_size,
                              hipStream_t stream)
{
  const float* x    = (const float*)d_in[0];
  const float* rmsw = (const float*)d_in[1];
  const float* gw   = (const float*)d_in[2];
  const float* w1   = (const float*)d_in[3];
  const float* w2   = (const float*)d_in[4];
  const float* w3   = (const float*)d_in[5];
  float* out = (float*)d_out;

  char* ws = (char*)d_ws;
  size_t o = 0;
  auto alloc = [&](size_t bytes) -> void* {
    void* p = ws + o;
    o += (bytes + 255) & ~(size_t)255;
    return p;
  };
  unsigned short* h_bf   = (unsigned short*)alloc((size_t)T_TOK*HDIM*2);
  int*   topk_i          = (int*)  alloc(T_TOK*2*4);
  float* topk_w          = (float*)alloc(T_TOK*2*4);
  int*   counters        = (int*)  alloc(64*4);   // count[8], cursor[8], offset[8]
  int*   jobs            = (int*)  alloc(NJOBS*4);
  int*   token_of_row    = (int*)  alloc(NROWS*4);
  float* wrow            = (float*)alloc(NROWS*4);
  int*   slot_of         = (int*)  alloc(T_TOK*2*4);
  unsigned short* act    = (unsigned short*)alloc((size_t)NROWS*IDIM*2);
  float* eo              = (float*)alloc((size_t)NROWS*HDIM*4);
  int* count  = counters;
  int* cursor = counters + 8;
  int* offset = counters + 16;

  // bf16 buffer for w2 only (w1/w3 converted in-GEMM now).
  bool havew2 = (ws_size >= o + (size_t)WELEM*2);
  unsigned short* w2bf = (unsigned short*)(ws + o);

  hipMemsetAsync(counters, 0, 64*4, stream);
  k_rms_router<<<T_TOK, 256, 0, stream>>>(x, rmsw, gw, h_bf, topk_i, topk_w, count);
  k_scan<<<1, 64, 0, stream>>>(count, offset, jobs);
  k_scatter<<<(T_TOK+255)/256, 256, 0, stream>>>(topk_i, topk_w, offset, cursor,
                                                 token_of_row, wrow, slot_of);
  k_mlp_in<<<NJOBS*56 + (havew2 ? CVTB : 0), 256, 0, stream>>>(
      h_bf, w1, w3, token_of_row, count, offset, jobs, act,
      (const float4*)w2, havew2 ? (uint2*)w2bf : (uint2*)nullptr);
  if (!havew2)
    k_cvt<<<2048, 256, 0, stream>>>((const float4*)w2, (uint2*)w2bf, WELEM/4);
  k_mlp_out<<<NJOBS*16, 256, 0, stream>>>(act, w2bf, wrow, count, offset, jobs, eo);
  k_combine<<<T_TOK, 256, 0, stream>>>(x, eo, slot_of, out);
}